// Round 9
// baseline (301.100 us; speedup 1.0000x reference)
//
#include <hip/hip_runtime.h>

// VectorQuantizer: x (32,64,64,64) f32, codebook (1024,64) f32
// out = concat( quantized (32,64,64,64) f32 , indices (32,64,64) as f32 )
//
// R9 = R8 with the rescan computing distances from UNBIASED exact-f32 cn.
//  - R8 post-mortem: R7/R8 failed bit-identically (fence changed nothing) ->
//    deterministic near-tie flips, not a race. Cause: rescan used cn+768,
//    whose [512,1024)-binade storage rounds cn by up to 3.05e-5; near-tie
//    positions (gap ~2e-5..6e-5) then order differently than the numpy f32
//    reference. R6's unbiased fmaf(-2,dot,cn) rescan was absmax-0-exact.
//  - Fix: prep writes BOTH cn+768 (MFMA C-operand; 3e-5 irrelevant vs the
//    0.1375 unflagged margin) and unbiased cn (rescan).
//  - Main path unchanged: single-product f16 MFMA, bias binade + 10-bit code
//    pack, u32 top-2 (4 VALU/dist), fused block-level exact-f32 rescan.

typedef _Float16 f16x8 __attribute__((ext_vector_type(8)));
typedef float    f32x4 __attribute__((ext_vector_type(4)));

#define VQ_D    64
#define VQ_HW   4096
#define VQ_NPOS 131072
#define BIAS    768.0f
#define EPS     0.2f
#define PMASK   0xFFFFFC00u
#define WS_CBN  32768      // f32 (cn+768)[1024]  — MFMA C-operand (biased)
#define WS_CBT  33792      // float4 cbT4[16384] (256 KB) — rescan codebook^T
#define WS_CBN2 99328      // f32 cn[1024] unbiased — rescan distances

// ---------- prep ----------
// bp[ct*128 + s*64 + lane], s in {0,1}: f16x8 of -2*f16(b) for B-cols
// n=ct*16+(lane&15), k0=s*32+(lane>>4)*8 (R6-verified fragment order).
__global__ __launch_bounds__(256)
void vq_prep(const float* __restrict__ cb, float* __restrict__ ws)
{
    const int tid = threadIdx.x;
    const int blk = blockIdx.x;
    if (blk < 32) {
        const int it   = blk * 256 + tid;            // [0, 8192)
        const int ct   = it >> 7;
        const int s    = (it >> 6) & 1;
        const int lane = it & 63;
        const int n    = ct * 16 + (lane & 15);
        const int k0   = s * 32 + (lane >> 4) * 8;
        const float* src = cb + n * 64 + k0;
        f16x8 o;
        #pragma unroll
        for (int j = 0; j < 8; ++j)
            o[j] = (_Float16)(-2.0f * (float)(_Float16)src[j]);
        ((f16x8*)ws)[it] = o;
    } else if (blk < 96) {
        const int it = (blk - 32) * 256 + tid;       // [0, 16384)
        const int k = it >> 4, j4 = it & 15;
        ((float4*)(ws + WS_CBT))[j4 * 1024 + k] = ((const float4*)cb)[it];
    } else {
        const int k = (blk - 96) * 256 + tid;        // [0, 1024)
        const float4* row = (const float4*)(cb + k * 64);
        float a0 = 0.f, a1 = 0.f, a2 = 0.f, a3 = 0.f;
        #pragma unroll
        for (int j = 0; j < 16; ++j) {
            const float4 c = row[j];
            a0 = fmaf(c.x, c.x, a0); a1 = fmaf(c.y, c.y, a1);
            a2 = fmaf(c.z, c.z, a2); a3 = fmaf(c.w, c.w, a3);
        }
        const float cn = (a0 + a1) + (a2 + a3);
        ws[WS_CBN  + k] = cn + BIAS;   // biased: MFMA C-operand only
        ws[WS_CBN2 + k] = cn;          // unbiased exact: rescan (R6-verified)
    }
}

// ---------- main ----------
#define PREFETCH(B0, B1, CV, CTN)                     \
    {                                                 \
        const f16x8* base_ = bp + (CTN) * 128;        \
        B0 = base_[lane]; B1 = base_[64 + lane];      \
        CV = cnb[(CTN) * 16 + m];                     \
    }

#define COMPUTE(B0, B1, CV, CTV)                                                            \
    {                                                                                       \
        const f32x4 Ci = {CV, CV, CV, CV};                                                  \
        f32x4 ac[4];                                                                        \
        _Pragma("unroll")                                                                   \
        for (int tl = 0; tl < 4; ++tl) {                                                    \
            ac[tl] = __builtin_amdgcn_mfma_f32_16x16x32_f16(Ah[tl][0], B0, Ci,     0,0,0);  \
            ac[tl] = __builtin_amdgcn_mfma_f32_16x16x32_f16(Ah[tl][1], B1, ac[tl], 0,0,0);  \
        }                                                                                   \
        const unsigned codev = (unsigned)((CTV) * 16 + m);                                  \
        _Pragma("unroll")                                                                   \
        for (int tl = 0; tl < 4; ++tl)                                                      \
            _Pragma("unroll")                                                               \
            for (int r = 0; r < 4; ++r) {                                                   \
                const unsigned u   = (__float_as_uint(ac[tl][r]) & PMASK) | codev;          \
                const unsigned old = d1p[tl][r];                                            \
                d1p[tl][r] = min(old, u);                                                   \
                d2p[tl][r] = min(d2p[tl][r], max(u, old));                                  \
            }                                                                               \
    }

__global__ __launch_bounds__(256, 2)
void vq_main(const float* __restrict__ x,
             const float* __restrict__ cb,
             const float* __restrict__ ws,
             float* __restrict__ out,
             float* __restrict__ idx_out)
{
    __shared__ int   sk[256];
    __shared__ float smg[256];
    __shared__ int   lds_list[256];
    __shared__ int   lds_cnt;
    __shared__ float rxs[4][VQ_D];

    const int tid  = threadIdx.x;
    const int lane = tid & 63;
    const int wv   = tid >> 6;
    const int m    = lane & 15;
    const int q    = lane >> 4;

    if (tid == 0) lds_cnt = 0;

    const f16x8* bp  = (const f16x8*)ws;
    const float* cnb = ws + WS_CBN;                  // cn + 768 (approx path)

    const int p0 = blockIdx.x * 256;                 // 256 consecutive positions
    const int b  = p0 >> 12;
    const int n0 = p0 & (VQ_HW - 1);
    const float* xw = x + (size_t)b * (VQ_D * VQ_HW) + n0 + wv * 64;

    // ---- A fragments (f16 hi only), 4 M-tiles, resident ----
    f16x8 Ah[4][2];
    #pragma unroll
    for (int tl = 0; tl < 4; ++tl)
        #pragma unroll
        for (int ks = 0; ks < 2; ++ks) {
            f16x8 h8;
            #pragma unroll
            for (int j = 0; j < 8; ++j) {
                const int k = ks * 32 + q * 8 + j;
                h8[j] = (_Float16)xw[(size_t)k * VQ_HW + tl * 16 + m];
            }
            Ah[tl][ks] = h8;
        }

    unsigned d1p[4][4], d2p[4][4];
    #pragma unroll
    for (int tl = 0; tl < 4; ++tl)
        #pragma unroll
        for (int r = 0; r < 4; ++r) { d1p[tl][r] = 0xFFFFFFFFu; d2p[tl][r] = 0xFFFFFFFFu; }

    // ping-pong B sets, prefetch distance 2 code-tiles
    f16x8 B0a, B1a, B0b, B1b;
    float cva, cvb;
    PREFETCH(B0a, B1a, cva, 0)
    PREFETCH(B0b, B1b, cvb, 1)

    for (int ct = 0; ct < 64; ct += 2) {
        COMPUTE(B0a, B1a, cva, ct)
        { const int ctn = (ct + 2 < 64) ? ct + 2 : 62; PREFETCH(B0a, B1a, cva, ctn) }
        COMPUTE(B0b, B1b, cvb, ct + 1)
        { const int ctn = (ct + 3 < 64) ? ct + 3 : 63; PREFETCH(B0b, B1b, cvb, ctn) }
    }

    // ---- packed top-2 merge across the 16 code-columns ----
    #pragma unroll
    for (int off = 1; off < 16; off <<= 1)
        #pragma unroll
        for (int tl = 0; tl < 4; ++tl)
            #pragma unroll
            for (int r = 0; r < 4; ++r) {
                const unsigned od1 = (unsigned)__shfl_xor((int)d1p[tl][r], off, 64);
                const unsigned od2 = (unsigned)__shfl_xor((int)d2p[tl][r], off, 64);
                const unsigned nd2 = min(max(d1p[tl][r], od1), min(d2p[tl][r], od2));
                d1p[tl][r] = min(d1p[tl][r], od1);
                d2p[tl][r] = nd2;
            }

    if (m == 0) {
        #pragma unroll
        for (int tl = 0; tl < 4; ++tl)
            #pragma unroll
            for (int r = 0; r < 4; ++r) {
                const int li = wv * 64 + tl * 16 + q * 4 + r;
                sk[li]  = (int)(d1p[tl][r] & 1023u);
                smg[li] = __uint_as_float(d2p[tl][r] & PMASK)
                        - __uint_as_float(d1p[tl][r] & PMASK);
            }
    }
    __syncthreads();

    // ---- epilogue: indices + quantized scatter (coalesced over n) ----
    idx_out[p0 + tid] = (float)sk[tid];
    const int bk = sk[tid];
    const float4* cr = (const float4*)(cb + (size_t)bk * VQ_D);
    float* ob = out + (size_t)b * (VQ_D * VQ_HW) + n0 + tid;
    #pragma unroll
    for (int d4 = 0; d4 < 16; ++d4) {
        const float4 v = cr[d4];
        ob[(size_t)(d4 * 4 + 0) * VQ_HW] = v.x;
        ob[(size_t)(d4 * 4 + 1) * VQ_HW] = v.y;
        ob[(size_t)(d4 * 4 + 2) * VQ_HW] = v.z;
        ob[(size_t)(d4 * 4 + 3) * VQ_HW] = v.w;
    }

    // ---- fused exact-f32 rescan for flagged positions (block-level) ----
    if (smg[tid] < EPS) {
        const int slot = atomicAdd(&lds_cnt, 1);
        lds_list[slot] = tid;
    }
    __syncthreads();   // drains epilogue stores (vmcnt0) before rescan overwrites

    const int nf = lds_cnt;
    const float* cbT = ws + WS_CBT;
    const float* cn2 = ws + WS_CBN2;                 // UNBIASED exact f32 norms
    for (int i = wv; i < nf; i += 4) {
        const int pi = lds_list[i];
        const int n  = n0 + pi;
        rxs[wv][lane] = x[(size_t)b * (VQ_D * VQ_HW) + (size_t)lane * VQ_HW + n];
        __threadfence_block();           // order ds_write before cross-lane reads
        float xv[VQ_D];
        #pragma unroll
        for (int d = 0; d < VQ_D; ++d) xv[d] = rxs[wv][d];

        float bd = 3.4e38f; int bk2 = 0;
        #pragma unroll 4
        for (int t = 0; t < 16; ++t) {
            const int code = t * 64 + lane;          // per-lane ascending
            float a0 = 0.f, a1 = 0.f, a2 = 0.f, a3 = 0.f;
            #pragma unroll
            for (int j4 = 0; j4 < 16; ++j4) {
                const float4 c = ((const float4*)cbT)[j4 * 1024 + code];
                a0 = fmaf(xv[j4 * 4 + 0], c.x, a0);
                a1 = fmaf(xv[j4 * 4 + 1], c.y, a1);
                a2 = fmaf(xv[j4 * 4 + 2], c.z, a2);
                a3 = fmaf(xv[j4 * 4 + 3], c.w, a3);
            }
            const float dist = fmaf(-2.0f, (a0 + a1) + (a2 + a3), cn2[code]);
            if (dist < bd) { bd = dist; bk2 = code; }
        }
        #pragma unroll
        for (int off = 1; off < 64; off <<= 1) {     // min dist, tie -> min k
            const float od = __shfl_xor(bd, off, 64);
            const int   ok = __shfl_xor(bk2, off, 64);
            if (od < bd || (od == bd && ok < bk2)) { bd = od; bk2 = ok; }
        }
        out[(size_t)b * (VQ_D * VQ_HW) + (size_t)lane * VQ_HW + n] =
            cb[(size_t)bk2 * VQ_D + lane];
        if (lane == 0) idx_out[p0 + pi] = (float)bk2;
    }
}

extern "C" void kernel_launch(void* const* d_in, const int* in_sizes, int n_in,
                              void* d_out, int out_size, void* d_ws, size_t ws_size,
                              hipStream_t stream) {
    const float* x  = (const float*)d_in[0];
    const float* cb = (const float*)d_in[1];
    float* out = (float*)d_out;
    float* idx = out + (size_t)VQ_NPOS * VQ_D;   // 8,388,608 floats in
    float* ws  = (float*)d_ws;                    // ~401 KB used

    vq_prep<<<dim3(100), dim3(256), 0, stream>>>(cb, ws);
    vq_main<<<dim3(512), dim3(256), 0, stream>>>(x, cb, ws, out, idx);
}

// Round 10
// 247.678 us; speedup vs baseline: 1.2157x; 1.2157x over previous
//
#include <hip/hip_runtime.h>

// VectorQuantizer: x (32,64,64,64) f32, codebook (1024,64) f32
// out = concat( quantized (32,64,64,64) f32 , indices (32,64,64) as f32 )
//
// R10 = R9 numerics (verified absmax 0) with the spill-free structure:
//  - R9 post-mortem: fusing the exact-f32 rescan (float xv[64]) into vq_main
//    made the allocator spill hot-path state (WRITE 47.7MB vs 33.3, FETCH
//    +14MB, MfmaUtil 2.7%, 250us). Rescan is now a separate kernel again
//    (R6-proven), fed UNBIASED cn2 (the R7/R8 bug was biased-cn rounding).
//  - Occupancy 2x: M=32 positions/wave (2 M-tiles), 128 positions/block,
//    grid 1024 = 4 blocks/CU = 4 waves/SIMD (R6 ran 2 waves/SIMD and sat at
//    3x its MFMA floor on B-prefetch latency). Total MFMA count unchanged.
//  - Main path per ct: 8 MFMA (single-product f16, cn+768 in C-operand),
//    packed u32 top-2 (4 VALU/dist), ping-pong B prefetch.

typedef _Float16 f16x8 __attribute__((ext_vector_type(8)));
typedef float    f32x4 __attribute__((ext_vector_type(4)));

#define VQ_D    64
#define VQ_HW   4096
#define VQ_NPOS 131072
#define BIAS    768.0f
#define EPS     0.2f
#define PMASK   0xFFFFFC00u
#define WS_CBN  32768      // f32 (cn+768)[1024] — MFMA C-operand (biased)
#define WS_CBT  33792      // float4 cbT4[16384] (256 KB) — rescan codebook^T
#define WS_CBN2 99328      // f32 cn[1024] unbiased — rescan distances
#define WS_CNT  100352     // int rescan counter
#define WS_LIST 100356     // int list[131072]

// ---------- prep ----------
// bp[ct*128 + s*64 + lane], s in {0,1}: f16x8 of -2*f16(b) for B-cols
// n=ct*16+(lane&15), k0=s*32+(lane>>4)*8 (R6-verified fragment order).
__global__ __launch_bounds__(256)
void vq_prep(const float* __restrict__ cb, float* __restrict__ ws)
{
    const int tid = threadIdx.x;
    const int blk = blockIdx.x;
    if (blk < 32) {
        const int it   = blk * 256 + tid;            // [0, 8192)
        const int ct   = it >> 7;
        const int s    = (it >> 6) & 1;
        const int lane = it & 63;
        const int n    = ct * 16 + (lane & 15);
        const int k0   = s * 32 + (lane >> 4) * 8;
        const float* src = cb + n * 64 + k0;
        f16x8 o;
        #pragma unroll
        for (int j = 0; j < 8; ++j)
            o[j] = (_Float16)(-2.0f * (float)(_Float16)src[j]);
        ((f16x8*)ws)[it] = o;
    } else if (blk < 96) {
        const int it = (blk - 32) * 256 + tid;       // [0, 16384)
        const int k = it >> 4, j4 = it & 15;
        ((float4*)(ws + WS_CBT))[j4 * 1024 + k] = ((const float4*)cb)[it];
    } else {
        const int k = (blk - 96) * 256 + tid;        // [0, 1024)
        const float4* row = (const float4*)(cb + k * 64);
        float a0 = 0.f, a1 = 0.f, a2 = 0.f, a3 = 0.f;
        #pragma unroll
        for (int j = 0; j < 16; ++j) {
            const float4 c = row[j];
            a0 = fmaf(c.x, c.x, a0); a1 = fmaf(c.y, c.y, a1);
            a2 = fmaf(c.z, c.z, a2); a3 = fmaf(c.w, c.w, a3);
        }
        const float cn = (a0 + a1) + (a2 + a3);
        ws[WS_CBN  + k] = cn + BIAS;   // biased: MFMA C-operand only
        ws[WS_CBN2 + k] = cn;          // unbiased exact: rescan
        if (k == 0) ((int*)ws)[WS_CNT] = 0;
    }
}

// ---------- main ----------
#define PREFETCH(B0, B1, CV, CTN)                     \
    {                                                 \
        const f16x8* base_ = bp + (CTN) * 128;        \
        B0 = base_[lane]; B1 = base_[64 + lane];      \
        CV = cnb[(CTN) * 16 + m];                     \
    }

#define COMPUTE(B0, B1, CV, CTV)                                                            \
    {                                                                                       \
        const f32x4 Ci = {CV, CV, CV, CV};                                                  \
        f32x4 ac[2];                                                                        \
        _Pragma("unroll")                                                                   \
        for (int tl = 0; tl < 2; ++tl) {                                                    \
            ac[tl] = __builtin_amdgcn_mfma_f32_16x16x32_f16(Ah[tl][0], B0, Ci,     0,0,0);  \
            ac[tl] = __builtin_amdgcn_mfma_f32_16x16x32_f16(Ah[tl][1], B1, ac[tl], 0,0,0);  \
        }                                                                                   \
        const unsigned codev = (unsigned)((CTV) * 16 + m);                                  \
        _Pragma("unroll")                                                                   \
        for (int tl = 0; tl < 2; ++tl)                                                      \
            _Pragma("unroll")                                                               \
            for (int r = 0; r < 4; ++r) {                                                   \
                const unsigned u   = (__float_as_uint(ac[tl][r]) & PMASK) | codev;          \
                const unsigned old = d1p[tl][r];                                            \
                d1p[tl][r] = min(old, u);                                                   \
                d2p[tl][r] = min(d2p[tl][r], max(u, old));                                  \
            }                                                                               \
    }

__global__ __launch_bounds__(256, 4)
void vq_main(const float* __restrict__ x,
             const float* __restrict__ cb,
             float* __restrict__ ws,
             float* __restrict__ out,
             float* __restrict__ idx_out)
{
    __shared__ int   sk[128];
    __shared__ float smg[128];

    const int tid  = threadIdx.x;
    const int lane = tid & 63;
    const int wv   = tid >> 6;
    const int m    = lane & 15;
    const int q    = lane >> 4;

    const f16x8* bp  = (const f16x8*)ws;
    const float* cnb = ws + WS_CBN;                  // cn + 768

    const int p0 = blockIdx.x * 128;                 // 128 consecutive positions
    const int b  = p0 >> 12;
    const int n0 = p0 & (VQ_HW - 1);
    const float* xw = x + (size_t)b * (VQ_D * VQ_HW) + n0 + wv * 32;

    // ---- A fragments (f16 hi only), 2 M-tiles/wave, resident ----
    f16x8 Ah[2][2];
    #pragma unroll
    for (int tl = 0; tl < 2; ++tl)
        #pragma unroll
        for (int ks = 0; ks < 2; ++ks) {
            f16x8 h8;
            #pragma unroll
            for (int j = 0; j < 8; ++j) {
                const int k = ks * 32 + q * 8 + j;
                h8[j] = (_Float16)xw[(size_t)k * VQ_HW + tl * 16 + m];
            }
            Ah[tl][ks] = h8;
        }

    unsigned d1p[2][4], d2p[2][4];
    #pragma unroll
    for (int tl = 0; tl < 2; ++tl)
        #pragma unroll
        for (int r = 0; r < 4; ++r) { d1p[tl][r] = 0xFFFFFFFFu; d2p[tl][r] = 0xFFFFFFFFu; }

    // ping-pong B sets, prefetch distance 2 code-tiles
    f16x8 B0a, B1a, B0b, B1b;
    float cva, cvb;
    PREFETCH(B0a, B1a, cva, 0)
    PREFETCH(B0b, B1b, cvb, 1)

    for (int ct = 0; ct < 64; ct += 2) {
        COMPUTE(B0a, B1a, cva, ct)
        { const int ctn = (ct + 2 < 64) ? ct + 2 : 62; PREFETCH(B0a, B1a, cva, ctn) }
        COMPUTE(B0b, B1b, cvb, ct + 1)
        { const int ctn = (ct + 3 < 64) ? ct + 3 : 63; PREFETCH(B0b, B1b, cvb, ctn) }
    }

    // ---- packed top-2 merge across the 16 code-columns ----
    #pragma unroll
    for (int off = 1; off < 16; off <<= 1)
        #pragma unroll
        for (int tl = 0; tl < 2; ++tl)
            #pragma unroll
            for (int r = 0; r < 4; ++r) {
                const unsigned od1 = (unsigned)__shfl_xor((int)d1p[tl][r], off, 64);
                const unsigned od2 = (unsigned)__shfl_xor((int)d2p[tl][r], off, 64);
                const unsigned nd2 = min(max(d1p[tl][r], od1), min(d2p[tl][r], od2));
                d1p[tl][r] = min(d1p[tl][r], od1);
                d2p[tl][r] = nd2;
            }

    if (m == 0) {
        #pragma unroll
        for (int tl = 0; tl < 2; ++tl)
            #pragma unroll
            for (int r = 0; r < 4; ++r) {
                const int li = wv * 32 + tl * 16 + q * 4 + r;
                sk[li]  = (int)(d1p[tl][r] & 1023u);
                smg[li] = __uint_as_float(d2p[tl][r] & PMASK)
                        - __uint_as_float(d1p[tl][r] & PMASK);
            }
    }
    __syncthreads();

    // ---- epilogue: indices + rescan flags + quantized scatter ----
    if (tid < 128) {
        idx_out[p0 + tid] = (float)sk[tid];
        if (smg[tid] < EPS) {
            const int slot = atomicAdd((int*)ws + WS_CNT, 1);
            ((int*)ws)[WS_LIST + slot] = p0 + tid;
        }
    }
    const int i    = tid & 127;          // position within block
    const int half = tid >> 7;           // dims [0,32) or [32,64)
    const int bk   = sk[i];
    const float4* cr = (const float4*)(cb + (size_t)bk * VQ_D) + half * 8;
    float* ob = out + (size_t)b * (VQ_D * VQ_HW) + n0 + i;
    #pragma unroll
    for (int q8 = 0; q8 < 8; ++q8) {
        const float4 v = cr[q8];
        const int d0 = half * 32 + q8 * 4;
        ob[(size_t)(d0 + 0) * VQ_HW] = v.x;
        ob[(size_t)(d0 + 1) * VQ_HW] = v.y;
        ob[(size_t)(d0 + 2) * VQ_HW] = v.z;
        ob[(size_t)(d0 + 3) * VQ_HW] = v.w;
    }
}

// ---------- rescan: exact f32 argmin for flagged positions (R6-verified) ----
__global__ __launch_bounds__(64)
void vq_rescan(const float* __restrict__ x,
               const float* __restrict__ cb,
               const float* __restrict__ ws,
               float* __restrict__ out,
               float* __restrict__ idx_out)
{
    __shared__ float xs[VQ_D];
    const int lane = threadIdx.x;
    const int cnt  = ((const int*)ws)[WS_CNT];
    const int* list = (const int*)ws + WS_LIST;
    const float*  cn2  = ws + WS_CBN2;               // unbiased exact f32 norms
    const float4* cbT4 = (const float4*)(ws + WS_CBT);

    for (int i = blockIdx.x; i < cnt; i += gridDim.x) {
        const int p = list[i];
        const int b = p >> 12, n = p & (VQ_HW - 1);
        xs[lane] = x[(size_t)b * (VQ_D * VQ_HW) + (size_t)lane * VQ_HW + n];
        __syncthreads();
        float4 xr[16];
        #pragma unroll
        for (int j = 0; j < 16; ++j) xr[j] = ((const float4*)xs)[j];

        float bd = 3.4e38f; int bk = 0;
        #pragma unroll 4
        for (int t = 0; t < 16; ++t) {
            const int code = t * 64 + lane;          // per-lane ascending
            float a0 = 0.f, a1 = 0.f, a2 = 0.f, a3 = 0.f;
            #pragma unroll
            for (int j4 = 0; j4 < 16; ++j4) {
                const float4 c = cbT4[j4 * 1024 + code];   // coalesced
                a0 = fmaf(xr[j4].x, c.x, a0); a1 = fmaf(xr[j4].y, c.y, a1);
                a2 = fmaf(xr[j4].z, c.z, a2); a3 = fmaf(xr[j4].w, c.w, a3);
            }
            const float dist = fmaf(-2.0f, (a0 + a1) + (a2 + a3), cn2[code]);
            if (dist < bd) { bd = dist; bk = code; }
        }
        #pragma unroll
        for (int off = 1; off < 64; off <<= 1) {     // min dist, tie -> min k
            const float od = __shfl_xor(bd, off, 64);
            const int   ok = __shfl_xor(bk, off, 64);
            if (od < bd || (od == bd && ok < bk)) { bd = od; bk = ok; }
        }
        out[(size_t)b * (VQ_D * VQ_HW) + (size_t)lane * VQ_HW + n] =
            cb[(size_t)bk * VQ_D + lane];
        if (lane == 0) idx_out[p] = (float)bk;
        __syncthreads();
    }
}

extern "C" void kernel_launch(void* const* d_in, const int* in_sizes, int n_in,
                              void* d_out, int out_size, void* d_ws, size_t ws_size,
                              hipStream_t stream) {
    const float* x  = (const float*)d_in[0];
    const float* cb = (const float*)d_in[1];
    float* out = (float*)d_out;
    float* idx = out + (size_t)VQ_NPOS * VQ_D;   // 8,388,608 floats in
    float* ws  = (float*)d_ws;                    // ~926 KB used

    vq_prep  <<<dim3(100),  dim3(256), 0, stream>>>(cb, ws);
    vq_main  <<<dim3(1024), dim3(256), 0, stream>>>(x, cb, ws, out, idx);
    vq_rescan<<<dim3(1024), dim3(64),  0, stream>>>(x, cb, ws, out, idx);
}

// Round 11
// 225.319 us; speedup vs baseline: 1.3363x; 1.0992x over previous
//
#include <hip/hip_runtime.h>

// VectorQuantizer: x (32,64,64,64) f32, codebook (1024,64) f32
// out = concat( quantized (32,64,64,64) f32 , indices (32,64,64) as f32 )
//
// R11 = R10 with the rescan restructured wave-granular.
//  - R10 post-mortem: rescan was 113 us (top dispatch) at cnt~4k (3% flag
//    rate, confirmed by WRITE line-sharing: 1-(1-p)^16 = 0.385 -> p=3.0%).
//    Cause: 1 wave/block, ~5-7 us serial latency per position (scattered x
//    gather + 256 L2 loads at ~6-deep MLP + store drain at __syncthreads),
//    x Poisson max ~13 positions/block over 1024 blocks.
//  - Fix: 1024 blocks x 256 threads = 4096 wave slots; wave-granular
//    grid-stride (deterministic <=1-2 positions/wave), per-wave LDS staging
//    with __threadfence_block + scalar reads (R9-proven), no __syncthreads.
//  - vq_prep / vq_main unchanged from R10 (passed, absmax 0).

typedef _Float16 f16x8 __attribute__((ext_vector_type(8)));
typedef float    f32x4 __attribute__((ext_vector_type(4)));

#define VQ_D    64
#define VQ_HW   4096
#define VQ_NPOS 131072
#define BIAS    768.0f
#define EPS     0.2f
#define PMASK   0xFFFFFC00u
#define WS_CBN  32768      // f32 (cn+768)[1024] — MFMA C-operand (biased)
#define WS_CBT  33792      // float4 cbT4[16384] (256 KB) — rescan codebook^T
#define WS_CBN2 99328      // f32 cn[1024] unbiased — rescan distances
#define WS_CNT  100352     // int rescan counter
#define WS_LIST 100356     // int list[131072]

// ---------- prep ----------
// bp[ct*128 + s*64 + lane], s in {0,1}: f16x8 of -2*f16(b) for B-cols
// n=ct*16+(lane&15), k0=s*32+(lane>>4)*8 (R6-verified fragment order).
__global__ __launch_bounds__(256)
void vq_prep(const float* __restrict__ cb, float* __restrict__ ws)
{
    const int tid = threadIdx.x;
    const int blk = blockIdx.x;
    if (blk < 32) {
        const int it   = blk * 256 + tid;            // [0, 8192)
        const int ct   = it >> 7;
        const int s    = (it >> 6) & 1;
        const int lane = it & 63;
        const int n    = ct * 16 + (lane & 15);
        const int k0   = s * 32 + (lane >> 4) * 8;
        const float* src = cb + n * 64 + k0;
        f16x8 o;
        #pragma unroll
        for (int j = 0; j < 8; ++j)
            o[j] = (_Float16)(-2.0f * (float)(_Float16)src[j]);
        ((f16x8*)ws)[it] = o;
    } else if (blk < 96) {
        const int it = (blk - 32) * 256 + tid;       // [0, 16384)
        const int k = it >> 4, j4 = it & 15;
        ((float4*)(ws + WS_CBT))[j4 * 1024 + k] = ((const float4*)cb)[it];
    } else {
        const int k = (blk - 96) * 256 + tid;        // [0, 1024)
        const float4* row = (const float4*)(cb + k * 64);
        float a0 = 0.f, a1 = 0.f, a2 = 0.f, a3 = 0.f;
        #pragma unroll
        for (int j = 0; j < 16; ++j) {
            const float4 c = row[j];
            a0 = fmaf(c.x, c.x, a0); a1 = fmaf(c.y, c.y, a1);
            a2 = fmaf(c.z, c.z, a2); a3 = fmaf(c.w, c.w, a3);
        }
        const float cn = (a0 + a1) + (a2 + a3);
        ws[WS_CBN  + k] = cn + BIAS;   // biased: MFMA C-operand only
        ws[WS_CBN2 + k] = cn;          // unbiased exact: rescan
        if (k == 0) ((int*)ws)[WS_CNT] = 0;
    }
}

// ---------- main (unchanged from R10) ----------
#define PREFETCH(B0, B1, CV, CTN)                     \
    {                                                 \
        const f16x8* base_ = bp + (CTN) * 128;        \
        B0 = base_[lane]; B1 = base_[64 + lane];      \
        CV = cnb[(CTN) * 16 + m];                     \
    }

#define COMPUTE(B0, B1, CV, CTV)                                                            \
    {                                                                                       \
        const f32x4 Ci = {CV, CV, CV, CV};                                                  \
        f32x4 ac[2];                                                                        \
        _Pragma("unroll")                                                                   \
        for (int tl = 0; tl < 2; ++tl) {                                                    \
            ac[tl] = __builtin_amdgcn_mfma_f32_16x16x32_f16(Ah[tl][0], B0, Ci,     0,0,0);  \
            ac[tl] = __builtin_amdgcn_mfma_f32_16x16x32_f16(Ah[tl][1], B1, ac[tl], 0,0,0);  \
        }                                                                                   \
        const unsigned codev = (unsigned)((CTV) * 16 + m);                                  \
        _Pragma("unroll")                                                                   \
        for (int tl = 0; tl < 2; ++tl)                                                      \
            _Pragma("unroll")                                                               \
            for (int r = 0; r < 4; ++r) {                                                   \
                const unsigned u   = (__float_as_uint(ac[tl][r]) & PMASK) | codev;          \
                const unsigned old = d1p[tl][r];                                            \
                d1p[tl][r] = min(old, u);                                                   \
                d2p[tl][r] = min(d2p[tl][r], max(u, old));                                  \
            }                                                                               \
    }

__global__ __launch_bounds__(256, 4)
void vq_main(const float* __restrict__ x,
             const float* __restrict__ cb,
             float* __restrict__ ws,
             float* __restrict__ out,
             float* __restrict__ idx_out)
{
    __shared__ int   sk[128];
    __shared__ float smg[128];

    const int tid  = threadIdx.x;
    const int lane = tid & 63;
    const int wv   = tid >> 6;
    const int m    = lane & 15;
    const int q    = lane >> 4;

    const f16x8* bp  = (const f16x8*)ws;
    const float* cnb = ws + WS_CBN;                  // cn + 768

    const int p0 = blockIdx.x * 128;                 // 128 consecutive positions
    const int b  = p0 >> 12;
    const int n0 = p0 & (VQ_HW - 1);
    const float* xw = x + (size_t)b * (VQ_D * VQ_HW) + n0 + wv * 32;

    // ---- A fragments (f16 hi only), 2 M-tiles/wave, resident ----
    f16x8 Ah[2][2];
    #pragma unroll
    for (int tl = 0; tl < 2; ++tl)
        #pragma unroll
        for (int ks = 0; ks < 2; ++ks) {
            f16x8 h8;
            #pragma unroll
            for (int j = 0; j < 8; ++j) {
                const int k = ks * 32 + q * 8 + j;
                h8[j] = (_Float16)xw[(size_t)k * VQ_HW + tl * 16 + m];
            }
            Ah[tl][ks] = h8;
        }

    unsigned d1p[2][4], d2p[2][4];
    #pragma unroll
    for (int tl = 0; tl < 2; ++tl)
        #pragma unroll
        for (int r = 0; r < 4; ++r) { d1p[tl][r] = 0xFFFFFFFFu; d2p[tl][r] = 0xFFFFFFFFu; }

    // ping-pong B sets, prefetch distance 2 code-tiles
    f16x8 B0a, B1a, B0b, B1b;
    float cva, cvb;
    PREFETCH(B0a, B1a, cva, 0)
    PREFETCH(B0b, B1b, cvb, 1)

    for (int ct = 0; ct < 64; ct += 2) {
        COMPUTE(B0a, B1a, cva, ct)
        { const int ctn = (ct + 2 < 64) ? ct + 2 : 62; PREFETCH(B0a, B1a, cva, ctn) }
        COMPUTE(B0b, B1b, cvb, ct + 1)
        { const int ctn = (ct + 3 < 64) ? ct + 3 : 63; PREFETCH(B0b, B1b, cvb, ctn) }
    }

    // ---- packed top-2 merge across the 16 code-columns ----
    #pragma unroll
    for (int off = 1; off < 16; off <<= 1)
        #pragma unroll
        for (int tl = 0; tl < 2; ++tl)
            #pragma unroll
            for (int r = 0; r < 4; ++r) {
                const unsigned od1 = (unsigned)__shfl_xor((int)d1p[tl][r], off, 64);
                const unsigned od2 = (unsigned)__shfl_xor((int)d2p[tl][r], off, 64);
                const unsigned nd2 = min(max(d1p[tl][r], od1), min(d2p[tl][r], od2));
                d1p[tl][r] = min(d1p[tl][r], od1);
                d2p[tl][r] = nd2;
            }

    if (m == 0) {
        #pragma unroll
        for (int tl = 0; tl < 2; ++tl)
            #pragma unroll
            for (int r = 0; r < 4; ++r) {
                const int li = wv * 32 + tl * 16 + q * 4 + r;
                sk[li]  = (int)(d1p[tl][r] & 1023u);
                smg[li] = __uint_as_float(d2p[tl][r] & PMASK)
                        - __uint_as_float(d1p[tl][r] & PMASK);
            }
    }
    __syncthreads();

    // ---- epilogue: indices + rescan flags + quantized scatter ----
    if (tid < 128) {
        idx_out[p0 + tid] = (float)sk[tid];
        if (smg[tid] < EPS) {
            const int slot = atomicAdd((int*)ws + WS_CNT, 1);
            ((int*)ws)[WS_LIST + slot] = p0 + tid;
        }
    }
    const int i    = tid & 127;          // position within block
    const int half = tid >> 7;           // dims [0,32) or [32,64)
    const int bk   = sk[i];
    const float4* cr = (const float4*)(cb + (size_t)bk * VQ_D) + half * 8;
    float* ob = out + (size_t)b * (VQ_D * VQ_HW) + n0 + i;
    #pragma unroll
    for (int q8 = 0; q8 < 8; ++q8) {
        const float4 v = cr[q8];
        const int d0 = half * 32 + q8 * 4;
        ob[(size_t)(d0 + 0) * VQ_HW] = v.x;
        ob[(size_t)(d0 + 1) * VQ_HW] = v.y;
        ob[(size_t)(d0 + 2) * VQ_HW] = v.z;
        ob[(size_t)(d0 + 3) * VQ_HW] = v.w;
    }
}

// ---------- rescan: wave-granular exact f32 argmin for flagged positions ----
__global__ __launch_bounds__(256)
void vq_rescan(const float* __restrict__ x,
               const float* __restrict__ cb,
               const float* __restrict__ ws,
               float* __restrict__ out,
               float* __restrict__ idx_out)
{
    __shared__ float rxs[4][VQ_D];       // per-wave x staging
    const int tid  = threadIdx.x;
    const int lane = tid & 63;
    const int wv   = tid >> 6;
    const int gw   = blockIdx.x * 4 + wv;        // global wave id
    const int gstride = gridDim.x * 4;           // 4096 wave slots

    const int cnt  = ((const int*)ws)[WS_CNT];
    const int* list = (const int*)ws + WS_LIST;
    const float*  cn2  = ws + WS_CBN2;           // unbiased exact f32 norms
    const float4* cbT4 = (const float4*)(ws + WS_CBT);

    for (int i = gw; i < cnt; i += gstride) {
        const int p = list[i];
        const int b = p >> 12, n = p & (VQ_HW - 1);
        rxs[wv][lane] = x[(size_t)b * (VQ_D * VQ_HW) + (size_t)lane * VQ_HW + n];
        __threadfence_block();           // R9-proven: order ds_write before reads
        float xv[VQ_D];                  // same-type scalar reads (no alias hoist)
        #pragma unroll
        for (int d = 0; d < VQ_D; ++d) xv[d] = rxs[wv][d];

        float bd = 3.4e38f; int bk = 0;
        #pragma unroll 4
        for (int t = 0; t < 16; ++t) {
            const int code = t * 64 + lane;      // per-lane ascending
            float a0 = 0.f, a1 = 0.f, a2 = 0.f, a3 = 0.f;
            #pragma unroll
            for (int j4 = 0; j4 < 16; ++j4) {
                const float4 c = cbT4[j4 * 1024 + code];   // coalesced
                a0 = fmaf(xv[j4 * 4 + 0], c.x, a0);
                a1 = fmaf(xv[j4 * 4 + 1], c.y, a1);
                a2 = fmaf(xv[j4 * 4 + 2], c.z, a2);
                a3 = fmaf(xv[j4 * 4 + 3], c.w, a3);
            }
            const float dist = fmaf(-2.0f, (a0 + a1) + (a2 + a3), cn2[code]);
            if (dist < bd) { bd = dist; bk = code; }
        }
        #pragma unroll
        for (int off = 1; off < 64; off <<= 1) { // min dist, tie -> min k
            const float od = __shfl_xor(bd, off, 64);
            const int   ok = __shfl_xor(bk, off, 64);
            if (od < bd || (od == bd && ok < bk)) { bd = od; bk = ok; }
        }
        out[(size_t)b * (VQ_D * VQ_HW) + (size_t)lane * VQ_HW + n] =
            cb[(size_t)bk * VQ_D + lane];
        if (lane == 0) idx_out[p] = (float)bk;
    }
}

extern "C" void kernel_launch(void* const* d_in, const int* in_sizes, int n_in,
                              void* d_out, int out_size, void* d_ws, size_t ws_size,
                              hipStream_t stream) {
    const float* x  = (const float*)d_in[0];
    const float* cb = (const float*)d_in[1];
    float* out = (float*)d_out;
    float* idx = out + (size_t)VQ_NPOS * VQ_D;   // 8,388,608 floats in
    float* ws  = (float*)d_ws;                    // ~926 KB used

    vq_prep  <<<dim3(100),  dim3(256), 0, stream>>>(cb, ws);
    vq_main  <<<dim3(1024), dim3(256), 0, stream>>>(x, cb, ws, out, idx);
    vq_rescan<<<dim3(1024), dim3(256), 0, stream>>>(x, cb, ws, out, idx);
}